// Round 1
// baseline (619.015 us; speedup 1.0000x reference)
//
#include <hip/hip_runtime.h>
#include <hip/hip_bf16.h>

// DeepSeek MLA prefill: T=2048, H=16, DN=128, DR=64, DV=128, QL=1536, KVL=512, HID=5120
// Strategy: convert everything to bf16, run all GEMMs on MFMA 16x16x32 bf16,
// flash attention with online softmax. All scratch in d_ws.

typedef __attribute__((ext_vector_type(8))) short bf16x8;
typedef __attribute__((ext_vector_type(4))) float f32x4;

#define T_SEQ 2048
#define NH 16
#define DNOPE 128
#define DROPE 64
#define DVAL 128
#define QLORA 1536
#define KVLORA 512
#define HID 5120
#define ATTN_SCALE 0.07216878364870323f  // (128+64)^-0.5

static __device__ __forceinline__ float bf2f(__hip_bfloat16 b) { return __bfloat162float(b); }

// ---------------------------------------------------------------- convert f32 -> bf16
__global__ void cvt_kernel(const float* __restrict__ in, __hip_bfloat16* __restrict__ out, int n) {
  for (int i = (blockIdx.x * 256 + threadIdx.x) * 4; i < n; i += gridDim.x * 256 * 4) {
    float4 v = *(const float4*)(in + i);
    out[i + 0] = __float2bfloat16(v.x);
    out[i + 1] = __float2bfloat16(v.y);
    out[i + 2] = __float2bfloat16(v.z);
    out[i + 3] = __float2bfloat16(v.w);
  }
}

// ------------------------------------------- transpose + convert: in[R][C] f32 -> out[C][R] bf16
__global__ void transpose_cvt_kernel(const float* __restrict__ in, __hip_bfloat16* __restrict__ out,
                                     int R, int C) {
  __shared__ float tile[32][33];
  int bi = blockIdx.x, bj = blockIdx.y;
  int tx = threadIdx.x & 31, ty = threadIdx.x >> 5;  // ty 0..7
#pragma unroll
  for (int k2 = 0; k2 < 4; k2++) {
    int r = bi * 32 + ty + k2 * 8;
    tile[ty + k2 * 8][tx] = in[(size_t)r * C + bj * 32 + tx];
  }
  __syncthreads();
#pragma unroll
  for (int k2 = 0; k2 < 4; k2++) {
    int cc = bj * 32 + ty + k2 * 8;
    out[(size_t)cc * R + bi * 32 + tx] = __float2bfloat16(tile[tx][ty + k2 * 8]);
  }
}

// ---------------------------------------------------------------- RMSNorm (f32 in, bf16 out)
__global__ void rmsnorm_kernel(const float* __restrict__ in, int in_stride, int cols,
                               const float* __restrict__ wgt,
                               __hip_bfloat16* __restrict__ out, int out_stride) {
  int row = blockIdx.x;
  const float* x = in + (size_t)row * in_stride;
  float ss = 0.f;
  for (int c = threadIdx.x; c < cols; c += 256) { float v = x[c]; ss += v * v; }
#pragma unroll
  for (int d = 1; d < 64; d <<= 1) ss += __shfl_xor(ss, d, 64);
  __shared__ float red[4];
  if ((threadIdx.x & 63) == 0) red[threadIdx.x >> 6] = ss;
  __syncthreads();
  float tot = red[0] + red[1] + red[2] + red[3];
  float r = rsqrtf(tot / cols + 1e-6f);
  __hip_bfloat16* o = out + (size_t)row * out_stride;
  for (int c = threadIdx.x; c < cols; c += 256)
    o[c] = __float2bfloat16(x[c] * r * wgt[c]);
}

// ---------------------------------------------------------------- RoPE on q (bf16 in-place)
// q[T][3072]; per head h, cols h*192+128 .. h*192+191 are the pe part, interleaved pairs.
__global__ void rope_q_kernel(__hip_bfloat16* __restrict__ q) {
  int row = blockIdx.x;
#pragma unroll
  for (int jj = 0; jj < 2; jj++) {
    int v = threadIdx.x + 256 * jj;  // 0..511
    int h = v >> 5, i = v & 31;
    float inv = powf(10000.f, -(2.f * i) / 64.f);
    float fr = (float)row * inv;
    float s, c;
    sincosf(fr, &s, &c);
    __hip_bfloat16* p = q + (size_t)row * 3072 + h * 192 + 128 + 2 * i;
    float x1 = bf2f(p[0]), x2 = bf2f(p[1]);
    p[0] = __float2bfloat16(x1 * c - x2 * s);
    p[1] = __float2bfloat16(x2 * c + x1 * s);
  }
}

// ---------------------------------------------------------------- RoPE on k_pe (f32 kv -> bf16)
__global__ void rope_k_kernel(const float* __restrict__ kv, __hip_bfloat16* __restrict__ kpe) {
  int row = blockIdx.x;
  int i = threadIdx.x;
  if (i < 32) {
    float inv = powf(10000.f, -(2.f * i) / 64.f);
    float fr = (float)row * inv;
    float s, c;
    sincosf(fr, &s, &c);
    float x1 = kv[(size_t)row * 576 + 512 + 2 * i];
    float x2 = kv[(size_t)row * 576 + 513 + 2 * i];
    kpe[(size_t)row * 64 + 2 * i]     = __float2bfloat16(x1 * c - x2 * s);
    kpe[(size_t)row * 64 + 2 * i + 1] = __float2bfloat16(x2 * c + x1 * s);
  }
}

// ---------------------------------------------------------------- GEMM: C[M][N] = A[M][K] * Bt[N][K]^T
// A bf16 row-major, Bt bf16 (pre-transposed weights), C f32 or bf16.
// 128x128 tile, BK=32, 4 waves of 64x64, reg-staged double-buffered LDS.
#define BT_PAD 40
template <bool OUT_BF16>
__global__ __launch_bounds__(256, 2) void gemm_bt_kernel(
    const __hip_bfloat16* __restrict__ A, const __hip_bfloat16* __restrict__ Bt,
    void* __restrict__ Cout, int M, int N, int K) {
  __shared__ __hip_bfloat16 As[2][128][BT_PAD];
  __shared__ __hip_bfloat16 Bs[2][128][BT_PAD];
  const int t = threadIdx.x;
  const int w = t >> 6, l = t & 63;
  const int lr = l & 15, lh = l >> 4;
  const int wr = w >> 1, wc = w & 1;
  const int bm = blockIdx.x, bn = blockIdx.y;

  const int arow = t >> 1;
  const int ak = (t & 1) * 16;
  const __hip_bfloat16* Aptr = A + (size_t)(bm * 128 + arow) * K + ak;
  int brow = bn * 128 + arow;
  if (brow >= N) brow = N - 1;  // clamp (N=576 tail tile); junk cols never stored
  const __hip_bfloat16* Bptr = Bt + (size_t)brow * K + ak;

  f32x4 acc[4][4];
#pragma unroll
  for (int i = 0; i < 4; i++)
#pragma unroll
    for (int j = 0; j < 4; j++) acc[i][j] = f32x4{0.f, 0.f, 0.f, 0.f};

  const int KT = K >> 5;
  bf16x8 ra0, ra1, rb0, rb1;
  ra0 = *(const bf16x8*)(Aptr);
  ra1 = *(const bf16x8*)(Aptr + 8);
  rb0 = *(const bf16x8*)(Bptr);
  rb1 = *(const bf16x8*)(Bptr + 8);
  *(bf16x8*)&As[0][arow][ak] = ra0;
  *(bf16x8*)&As[0][arow][ak + 8] = ra1;
  *(bf16x8*)&Bs[0][arow][ak] = rb0;
  *(bf16x8*)&Bs[0][arow][ak + 8] = rb1;

  int cur = 0;
  for (int kt = 0; kt < KT; ++kt) {
    if (kt + 1 < KT) {  // issue next-tile global loads early (hide under compute)
      const __hip_bfloat16* ap = Aptr + (kt + 1) * 32;
      const __hip_bfloat16* bp = Bptr + (kt + 1) * 32;
      ra0 = *(const bf16x8*)(ap);
      ra1 = *(const bf16x8*)(ap + 8);
      rb0 = *(const bf16x8*)(bp);
      rb1 = *(const bf16x8*)(bp + 8);
    }
    __syncthreads();
    bf16x8 af[4], bff[4];
#pragma unroll
    for (int m = 0; m < 4; m++) af[m] = *(bf16x8*)&As[cur][wr * 64 + m * 16 + lr][lh * 8];
#pragma unroll
    for (int n = 0; n < 4; n++) bff[n] = *(bf16x8*)&Bs[cur][wc * 64 + n * 16 + lr][lh * 8];
#pragma unroll
    for (int m = 0; m < 4; m++)
#pragma unroll
      for (int n = 0; n < 4; n++)
        acc[m][n] = __builtin_amdgcn_mfma_f32_16x16x32_bf16(af[m], bff[n], acc[m][n], 0, 0, 0);
    __syncthreads();
    if (kt + 1 < KT) {
      int nb = cur ^ 1;
      *(bf16x8*)&As[nb][arow][ak] = ra0;
      *(bf16x8*)&As[nb][arow][ak + 8] = ra1;
      *(bf16x8*)&Bs[nb][arow][ak] = rb0;
      *(bf16x8*)&Bs[nb][arow][ak + 8] = rb1;
      cur = nb;
    }
  }
#pragma unroll
  for (int m = 0; m < 4; m++) {
    int row = bm * 128 + wr * 64 + m * 16 + lh * 4;
#pragma unroll
    for (int n = 0; n < 4; n++) {
      int col = bn * 128 + wc * 64 + n * 16 + lr;
      if (col < N) {
#pragma unroll
        for (int j = 0; j < 4; j++) {
          if (OUT_BF16)
            ((__hip_bfloat16*)Cout)[(size_t)(row + j) * N + col] = __float2bfloat16(acc[m][n][j]);
          else
            ((float*)Cout)[(size_t)(row + j) * N + col] = acc[m][n][j];
        }
      }
    }
  }
}

// ---------------------------------------------------------------- flash attention (causal)
// Q[T][3072] (roped), KVB[T][4096] (h*256: 0..127 k_nope, 128..255 v), KPE[T][64] (roped, shared)
// Out[T][2048] bf16 (h*128+dv). Block = (64 q-rows, 1 head), 4 waves x 16 rows, k-blocks of 64.
__global__ __launch_bounds__(256, 2) void attn_kernel(
    const __hip_bfloat16* __restrict__ Q, const __hip_bfloat16* __restrict__ KVB,
    const __hip_bfloat16* __restrict__ KPE, __hip_bfloat16* __restrict__ Out) {
  __shared__ __hip_bfloat16 Ks[64][200];     // K rows (192 feat + pad)
  __shared__ __hip_bfloat16 Vs[128][72];     // V transposed [dv][s], chunk-swizzled in s
  __shared__ __hip_bfloat16 Ps[4][16][72];   // per-wave P slab

  const int t = threadIdx.x;
  const int w = t >> 6, l = t & 63;
  const int lr = l & 15, lh = l >> 4;
  const int bm = (int)gridDim.x - 1 - (int)blockIdx.x;  // heavy blocks first
  const int h = blockIdx.y;

  // Q fragments held in registers for the whole kernel
  bf16x8 aq[6];
  const int qrow = bm * 64 + w * 16 + lr;
  const __hip_bfloat16* qp = Q + (size_t)qrow * 3072 + h * 192 + lh * 8;
#pragma unroll
  for (int ks = 0; ks < 6; ks++) aq[ks] = *(const bf16x8*)(qp + ks * 32);

  f32x4 o_acc[8];
#pragma unroll
  for (int i = 0; i < 8; i++) o_acc[i] = f32x4{0.f, 0.f, 0.f, 0.f};
  float m_run[4], l_run[4];
#pragma unroll
  for (int j = 0; j < 4; j++) { m_run[j] = -INFINITY; l_run[j] = 0.f; }

  for (int kb = 0; kb <= bm; ++kb) {
    const int s0 = kb * 64;
    // stage K tile: [64][192] = k_nope | k_pe
#pragma unroll
    for (int j = 0; j < 6; j++) {
      int c = t + 256 * j;
      int row = c / 24;
      int col8 = (c % 24) * 8;
      const __hip_bfloat16* src;
      if (col8 < 128) src = KVB + (size_t)(s0 + row) * 4096 + h * 256 + col8;
      else            src = KPE + (size_t)(s0 + row) * 64 + (col8 - 128);
      *(bf16x8*)&Ks[row][col8] = *(const bf16x8*)src;
    }
    // stage V transposed, XOR-swizzled s-chunks to kill write bank conflicts
#pragma unroll
    for (int j = 0; j < 4; j++) {
      int c = t + 256 * j;
      int srow = c >> 4;
      int dv8 = (c & 15) * 8;
      bf16x8 v = *(const bf16x8*)(KVB + (size_t)(s0 + srow) * 4096 + h * 256 + 128 + dv8);
      int sc = srow >> 3, sl = srow & 7;
#pragma unroll
      for (int i = 0; i < 8; i++) {
        int dv = dv8 + i;
        Vs[dv][((sc ^ ((dv >> 3) & 7)) << 3) | sl] = ((__hip_bfloat16*)&v)[i];
      }
    }
    __syncthreads();

    // S = Q K^T  (16x64 per wave, K-dim 192 = 6 MFMA steps)
    f32x4 sa[4];
#pragma unroll
    for (int nf = 0; nf < 4; nf++) sa[nf] = f32x4{0.f, 0.f, 0.f, 0.f};
#pragma unroll
    for (int ks = 0; ks < 6; ks++) {
#pragma unroll
      for (int nf = 0; nf < 4; nf++) {
        bf16x8 b = *(bf16x8*)&Ks[nf * 16 + lr][ks * 32 + lh * 8];
        sa[nf] = __builtin_amdgcn_mfma_f32_16x16x32_bf16(aq[ks], b, sa[nf], 0, 0, 0);
      }
    }
    // scale + causal mask
    float sv[4][4];
    const bool diag = (kb == bm);
#pragma unroll
    for (int nf = 0; nf < 4; nf++) {
      int scol = s0 + nf * 16 + lr;
#pragma unroll
      for (int j = 0; j < 4; j++) {
        float x = sa[nf][j] * ATTN_SCALE;
        if (diag) {
          int qr = bm * 64 + w * 16 + lh * 4 + j;
          if (scol > qr) x = -1e30f;
        }
        sv[nf][j] = x;
      }
    }
    // online softmax (rows live across 16 lanes sharing lh)
    float pm[4], fac[4];
#pragma unroll
    for (int j = 0; j < 4; j++) {
      float mx = fmaxf(fmaxf(sv[0][j], sv[1][j]), fmaxf(sv[2][j], sv[3][j]));
#pragma unroll
      for (int d = 1; d < 16; d <<= 1) mx = fmaxf(mx, __shfl_xor(mx, d, 64));
      float mn = fmaxf(m_run[j], mx);
      fac[j] = __expf(m_run[j] - mn);
      m_run[j] = mn;
      pm[j] = mn;
    }
    float rs[4] = {0.f, 0.f, 0.f, 0.f};
#pragma unroll
    for (int nf = 0; nf < 4; nf++) {
#pragma unroll
      for (int j = 0; j < 4; j++) {
        float p = __expf(sv[nf][j] - pm[j]);
        rs[j] += p;
        Ps[w][lh * 4 + j][nf * 16 + lr] = __float2bfloat16(p);
      }
    }
#pragma unroll
    for (int j = 0; j < 4; j++) {
      float s = rs[j];
#pragma unroll
      for (int d = 1; d < 16; d <<= 1) s += __shfl_xor(s, d, 64);
      l_run[j] = l_run[j] * fac[j] + s;
    }
#pragma unroll
    for (int nf = 0; nf < 8; nf++)
#pragma unroll
      for (int j = 0; j < 4; j++) o_acc[nf][j] *= fac[j];

    // PV: O += P[16x64] * V[64x128]
#pragma unroll
    for (int ks = 0; ks < 2; ks++) {
      bf16x8 pa = *(bf16x8*)&Ps[w][lr][ks * 32 + lh * 8];
#pragma unroll
      for (int nf = 0; nf < 8; nf++) {
        int dv = nf * 16 + lr;
        int c8 = ks * 4 + lh;
        bf16x8 vb = *(bf16x8*)&Vs[dv][((c8 ^ ((dv >> 3) & 7)) << 3)];
        o_acc[nf] = __builtin_amdgcn_mfma_f32_16x16x32_bf16(pa, vb, o_acc[nf], 0, 0, 0);
      }
    }
    __syncthreads();
  }
  // epilogue: normalize and store
#pragma unroll
  for (int nf = 0; nf < 8; nf++) {
    int col = h * 128 + nf * 16 + lr;
#pragma unroll
    for (int j = 0; j < 4; j++) {
      int row = bm * 64 + w * 16 + lh * 4 + j;
      Out[(size_t)row * 2048 + col] = __float2bfloat16(o_acc[nf][j] / l_run[j]);
    }
  }
}

// ----------------------------------------------------------------------------------------
extern "C" void kernel_launch(void* const* d_in, const int* in_sizes, int n_in,
                              void* d_out, int out_size, void* d_ws, size_t ws_size,
                              hipStream_t stream) {
  const float* hidden  = (const float*)d_in[1];
  const float* wq_a    = (const float*)d_in[2];
  const float* q_a_ln  = (const float*)d_in[3];
  const float* wq_b    = (const float*)d_in[4];
  const float* wkv_a   = (const float*)d_in[5];
  const float* kv_a_ln = (const float*)d_in[6];
  const float* wkv_b   = (const float*)d_in[7];
  const float* wo      = (const float*)d_in[8];
  float* out = (float*)d_out;

  char* ws = (char*)d_ws;
  size_t off = 0;
  auto alloc = [&](size_t bytes) { void* p = ws + off; off += (bytes + 255) & ~(size_t)255; return p; };
  __hip_bfloat16* h_bf    = (__hip_bfloat16*)alloc((size_t)2048 * 5120 * 2);
  __hip_bfloat16* wq_a_t  = (__hip_bfloat16*)alloc((size_t)1536 * 5120 * 2);
  __hip_bfloat16* wq_b_t  = (__hip_bfloat16*)alloc((size_t)3072 * 1536 * 2);
  __hip_bfloat16* wkv_a_t = (__hip_bfloat16*)alloc((size_t)576 * 5120 * 2);
  __hip_bfloat16* wkv_b_t = (__hip_bfloat16*)alloc((size_t)4096 * 512 * 2);
  __hip_bfloat16* wo_t    = (__hip_bfloat16*)alloc((size_t)5120 * 2048 * 2);
  float*          q_lat   = (float*)alloc((size_t)2048 * 1536 * 4);
  float*          kv_f    = (float*)alloc((size_t)2048 * 576 * 4);
  __hip_bfloat16* q_a_bf  = (__hip_bfloat16*)alloc((size_t)2048 * 1536 * 2);
  __hip_bfloat16* ckv_bf  = (__hip_bfloat16*)alloc((size_t)2048 * 512 * 2);
  __hip_bfloat16* kpe_bf  = (__hip_bfloat16*)alloc((size_t)2048 * 64 * 2);
  __hip_bfloat16* q_bf    = (__hip_bfloat16*)alloc((size_t)2048 * 3072 * 2);
  __hip_bfloat16* kvb_bf  = (__hip_bfloat16*)alloc((size_t)2048 * 4096 * 2);
  __hip_bfloat16* attn_o  = (__hip_bfloat16*)alloc((size_t)2048 * 2048 * 2);
  (void)ws_size; (void)in_sizes; (void)n_in; (void)out_size;

  // conversions
  cvt_kernel<<<1024, 256, 0, stream>>>(hidden, h_bf, 2048 * 5120);
  transpose_cvt_kernel<<<dim3(5120 / 32, 1536 / 32), 256, 0, stream>>>(wq_a, wq_a_t, 5120, 1536);
  transpose_cvt_kernel<<<dim3(1536 / 32, 3072 / 32), 256, 0, stream>>>(wq_b, wq_b_t, 1536, 3072);
  transpose_cvt_kernel<<<dim3(5120 / 32, 576 / 32), 256, 0, stream>>>(wkv_a, wkv_a_t, 5120, 576);
  transpose_cvt_kernel<<<dim3(512 / 32, 4096 / 32), 256, 0, stream>>>(wkv_b, wkv_b_t, 512, 4096);
  transpose_cvt_kernel<<<dim3(2048 / 32, 5120 / 32), 256, 0, stream>>>(wo, wo_t, 2048, 5120);

  // q_latent = hidden @ wq_a ; kv = hidden @ wkv_a
  gemm_bt_kernel<false><<<dim3(16, 12), 256, 0, stream>>>(h_bf, wq_a_t, q_lat, 2048, 1536, 5120);
  gemm_bt_kernel<false><<<dim3(16, 5), 256, 0, stream>>>(h_bf, wkv_a_t, kv_f, 2048, 576, 5120);

  // norms + k rope
  rmsnorm_kernel<<<2048, 256, 0, stream>>>(q_lat, 1536, 1536, q_a_ln, q_a_bf, 1536);
  rmsnorm_kernel<<<2048, 256, 0, stream>>>(kv_f, 576, 512, kv_a_ln, ckv_bf, 512);
  rope_k_kernel<<<2048, 64, 0, stream>>>(kv_f, kpe_bf);

  // q = q_a_norm @ wq_b, then rope the pe slices in-place
  gemm_bt_kernel<true><<<dim3(16, 24), 256, 0, stream>>>(q_a_bf, wq_b_t, q_bf, 2048, 3072, 1536);
  rope_q_kernel<<<2048, 256, 0, stream>>>(q_bf);

  // kvb = c_kv @ wkv_b  (k_nope | v per head)
  gemm_bt_kernel<true><<<dim3(16, 32), 256, 0, stream>>>(ckv_bf, wkv_b_t, kvb_bf, 2048, 4096, 512);

  // causal flash attention
  attn_kernel<<<dim3(32, 16), 256, 0, stream>>>(q_bf, kvb_bf, kpe_bf, attn_o);

  // final projection
  gemm_bt_kernel<false><<<dim3(16, 40), 256, 0, stream>>>(attn_o, wo_t, out, 2048, 5120, 2048);
}

// Round 3
// 547.942 us; speedup vs baseline: 1.1297x; 1.1297x over previous
//
#include <hip/hip_runtime.h>
#include <hip/hip_bf16.h>

typedef __attribute__((ext_vector_type(8))) short bf16x8;
typedef __attribute__((ext_vector_type(4))) float f32x4;

typedef __attribute__((address_space(1))) const unsigned int gu32;
typedef __attribute__((address_space(3))) unsigned int lu32;

#define ATTN_SCALE 0.07216878364870323f  // (128+64)^-0.5

static __device__ __forceinline__ float bf2f(__hip_bfloat16 b) { return __bfloat162float(b); }

// ---------------------------------------------------------------- convert f32 -> bf16
__global__ void cvt_kernel(const float* __restrict__ in, __hip_bfloat16* __restrict__ out, int n) {
  for (int i = (blockIdx.x * 256 + threadIdx.x) * 4; i < n; i += gridDim.x * 256 * 4) {
    float4 v = *(const float4*)(in + i);
    out[i + 0] = __float2bfloat16(v.x);
    out[i + 1] = __float2bfloat16(v.y);
    out[i + 2] = __float2bfloat16(v.z);
    out[i + 3] = __float2bfloat16(v.w);
  }
}

// ------------------------------------------- transpose + convert: in[R][C] f32 -> out[C][R] bf16
__global__ void transpose_cvt_kernel(const float* __restrict__ in, __hip_bfloat16* __restrict__ out,
                                     int R, int C) {
  __shared__ float tile[32][33];
  int bi = blockIdx.x, bj = blockIdx.y;
  int tx = threadIdx.x & 31, ty = threadIdx.x >> 5;  // ty 0..7
#pragma unroll
  for (int k2 = 0; k2 < 4; k2++) {
    int r = bi * 32 + ty + k2 * 8;
    tile[ty + k2 * 8][tx] = in[(size_t)r * C + bj * 32 + tx];
  }
  __syncthreads();
#pragma unroll
  for (int k2 = 0; k2 < 4; k2++) {
    int cc = bj * 32 + ty + k2 * 8;
    out[(size_t)cc * R + bi * 32 + tx] = __float2bfloat16(tile[tx][ty + k2 * 8]);
  }
}

// ---------------------------------------------------------------- RMSNorm (f32 in, bf16 out)
__global__ void rmsnorm_kernel(const float* __restrict__ in, int in_stride, int cols,
                               const float* __restrict__ wgt,
                               __hip_bfloat16* __restrict__ out, int out_stride) {
  int row = blockIdx.x;
  const float* x = in + (size_t)row * in_stride;
  float ss = 0.f;
  for (int c = threadIdx.x; c < cols; c += 256) { float v = x[c]; ss += v * v; }
#pragma unroll
  for (int d = 1; d < 64; d <<= 1) ss += __shfl_xor(ss, d, 64);
  __shared__ float red[4];
  if ((threadIdx.x & 63) == 0) red[threadIdx.x >> 6] = ss;
  __syncthreads();
  float tot = red[0] + red[1] + red[2] + red[3];
  float r = rsqrtf(tot / cols + 1e-6f);
  __hip_bfloat16* o = out + (size_t)row * out_stride;
  for (int c = threadIdx.x; c < cols; c += 256)
    o[c] = __float2bfloat16(x[c] * r * wgt[c]);
}

// ---------------------------------------------------------------- RoPE on q (bf16 in-place)
__global__ void rope_q_kernel(__hip_bfloat16* __restrict__ q) {
  int row = blockIdx.x;
#pragma unroll
  for (int jj = 0; jj < 2; jj++) {
    int v = threadIdx.x + 256 * jj;  // 0..511
    int h = v >> 5, i = v & 31;
    float inv = powf(10000.f, -(2.f * i) / 64.f);
    float fr = (float)row * inv;
    float s, c;
    sincosf(fr, &s, &c);
    __hip_bfloat16* p = q + (size_t)row * 3072 + h * 192 + 128 + 2 * i;
    float x1 = bf2f(p[0]), x2 = bf2f(p[1]);
    p[0] = __float2bfloat16(x1 * c - x2 * s);
    p[1] = __float2bfloat16(x2 * c + x1 * s);
  }
}

// ---------------------------------------------------------------- RoPE on k_pe (f32 src -> bf16)
__global__ void rope_k_kernel(const float* __restrict__ src, int stride,
                              __hip_bfloat16* __restrict__ kpe) {
  int row = blockIdx.x;
  int i = threadIdx.x;
  if (i < 32) {
    float inv = powf(10000.f, -(2.f * i) / 64.f);
    float fr = (float)row * inv;
    float s, c;
    sincosf(fr, &s, &c);
    float x1 = src[(size_t)row * stride + 2 * i];
    float x2 = src[(size_t)row * stride + 2 * i + 1];
    kpe[(size_t)row * 64 + 2 * i]     = __float2bfloat16(x1 * c - x2 * s);
    kpe[(size_t)row * 64 + 2 * i + 1] = __float2bfloat16(x2 * c + x1 * s);
  }
}

// ---------------------------------------------------------------- GEMM: C[M][N] = A[M][K] * Bt[N][K]^T
// m97-style: global_load_lds(16B) staging, linear [128][32] LDS double-buffered,
// ONE barrier per K-step (DMA for k+1 issued right after the barrier, drained at next barrier).
template <bool OUT_BF16>
__global__ __launch_bounds__(256, 2) void gemm_lds_kernel(
    const __hip_bfloat16* __restrict__ A, const __hip_bfloat16* __restrict__ Bt,
    void* __restrict__ Cout, int M, int N, int K) {
  __shared__ __hip_bfloat16 As[2][128][32];
  __shared__ __hip_bfloat16 Bs[2][128][32];
  const int t = threadIdx.x;
  const int w = t >> 6, l = t & 63;
  const int lr = l & 15, lh = l >> 4;
  const int wr = w >> 1, wc = w & 1;
  const int bm = blockIdx.x, bn = blockIdx.y;

  // staging: tile = 8 chunks of 1KB; wave w writes chunks {w, w+4}.
  // lane l -> row (l>>2) within chunk, col (l&3)*8; LDS offset == wave_base + l*16 (linear rule).
  const int r0 = l >> 2;
  const int c0 = (l & 3) * 8;
  const int rowA0 = w * 16 + r0;
  const int rowA1 = (4 + w) * 16 + r0;
  const __hip_bfloat16* Ag0 = A + (size_t)(bm * 128 + rowA0) * K + c0;
  const __hip_bfloat16* Ag1 = A + (size_t)(bm * 128 + rowA1) * K + c0;
  int br0 = bn * 128 + rowA0; if (br0 >= N) br0 = N - 1;  // clamp: junk cols never stored
  int br1 = bn * 128 + rowA1; if (br1 >= N) br1 = N - 1;
  const __hip_bfloat16* Bg0 = Bt + (size_t)br0 * K + c0;
  const __hip_bfloat16* Bg1 = Bt + (size_t)br1 * K + c0;

  f32x4 acc[4][4];
#pragma unroll
  for (int i = 0; i < 4; i++)
#pragma unroll
    for (int j = 0; j < 4; j++) acc[i][j] = f32x4{0.f, 0.f, 0.f, 0.f};

  auto issue = [&](int kt, int buf) {
    const int ko = kt * 32;
    __builtin_amdgcn_global_load_lds((gu32*)(Ag0 + ko), (lu32*)&As[buf][rowA0][c0], 16, 0, 0);
    __builtin_amdgcn_global_load_lds((gu32*)(Ag1 + ko), (lu32*)&As[buf][rowA1][c0], 16, 0, 0);
    __builtin_amdgcn_global_load_lds((gu32*)(Bg0 + ko), (lu32*)&Bs[buf][rowA0][c0], 16, 0, 0);
    __builtin_amdgcn_global_load_lds((gu32*)(Bg1 + ko), (lu32*)&Bs[buf][rowA1][c0], 16, 0, 0);
  };

  const int KT = K >> 5;
  issue(0, 0);
  int cur = 0;
  for (int kt = 0; kt < KT; ++kt) {
    __syncthreads();  // drains this wave's DMA (vmcnt0) -> buf `cur` ready; all waves past reads of cur^1
    if (kt + 1 < KT) issue(kt + 1, cur ^ 1);  // overlaps with compute; drains at next barrier
    bf16x8 af[4], bff[4];
#pragma unroll
    for (int m = 0; m < 4; m++) af[m] = *(bf16x8*)&As[cur][wr * 64 + m * 16 + lr][lh * 8];
#pragma unroll
    for (int n = 0; n < 4; n++) bff[n] = *(bf16x8*)&Bs[cur][wc * 64 + n * 16 + lr][lh * 8];
    __builtin_amdgcn_s_setprio(1);
#pragma unroll
    for (int m = 0; m < 4; m++)
#pragma unroll
      for (int n = 0; n < 4; n++)
        acc[m][n] = __builtin_amdgcn_mfma_f32_16x16x32_bf16(af[m], bff[n], acc[m][n], 0, 0, 0);
    __builtin_amdgcn_s_setprio(0);
    cur ^= 1;
  }
#pragma unroll
  for (int m = 0; m < 4; m++) {
    int row = bm * 128 + wr * 64 + m * 16 + lh * 4;
#pragma unroll
    for (int n = 0; n < 4; n++) {
      int col = bn * 128 + wc * 64 + n * 16 + lr;
      if (col < N) {
#pragma unroll
        for (int j = 0; j < 4; j++) {
          if (OUT_BF16)
            ((__hip_bfloat16*)Cout)[(size_t)(row + j) * N + col] = __float2bfloat16(acc[m][n][j]);
          else
            ((float*)Cout)[(size_t)(row + j) * N + col] = acc[m][n][j];
        }
      }
    }
  }
}

// ---------------------------------------------------------------- flash attention (causal)
// ROUND-1 PROVEN VERSION (verbatim). Q[T][3072] roped; KVB[T][4096] (h*256: k_nope|v);
// KPE[T][64]; Out[T][2048]. Block = (64 q-rows, 1 head), 4 waves x 16 rows, k-blocks of 64.
__global__ __launch_bounds__(256, 2) void attn_kernel(
    const __hip_bfloat16* __restrict__ Q, const __hip_bfloat16* __restrict__ KVB,
    const __hip_bfloat16* __restrict__ KPE, __hip_bfloat16* __restrict__ Out) {
  __shared__ __hip_bfloat16 Ks[64][200];     // K rows (192 feat + pad)
  __shared__ __hip_bfloat16 Vs[128][72];     // V transposed [dv][s], chunk-swizzled in s
  __shared__ __hip_bfloat16 Ps[4][16][72];   // per-wave P slab

  const int t = threadIdx.x;
  const int w = t >> 6, l = t & 63;
  const int lr = l & 15, lh = l >> 4;
  const int bm = (int)gridDim.x - 1 - (int)blockIdx.x;  // heavy blocks first
  const int h = blockIdx.y;

  // Q fragments held in registers for the whole kernel
  bf16x8 aq[6];
  const int qrow = bm * 64 + w * 16 + lr;
  const __hip_bfloat16* qp = Q + (size_t)qrow * 3072 + h * 192 + lh * 8;
#pragma unroll
  for (int ks = 0; ks < 6; ks++) aq[ks] = *(const bf16x8*)(qp + ks * 32);

  f32x4 o_acc[8];
#pragma unroll
  for (int i = 0; i < 8; i++) o_acc[i] = f32x4{0.f, 0.f, 0.f, 0.f};
  float m_run[4], l_run[4];
#pragma unroll
  for (int j = 0; j < 4; j++) { m_run[j] = -INFINITY; l_run[j] = 0.f; }

  for (int kb = 0; kb <= bm; ++kb) {
    const int s0 = kb * 64;
    // stage K tile: [64][192] = k_nope | k_pe
#pragma unroll
    for (int j = 0; j < 6; j++) {
      int c = t + 256 * j;
      int row = c / 24;
      int col8 = (c % 24) * 8;
      const __hip_bfloat16* src;
      if (col8 < 128) src = KVB + (size_t)(s0 + row) * 4096 + h * 256 + col8;
      else            src = KPE + (size_t)(s0 + row) * 64 + (col8 - 128);
      *(bf16x8*)&Ks[row][col8] = *(const bf16x8*)src;
    }
    // stage V transposed, XOR-swizzled s-chunks to kill write bank conflicts
#pragma unroll
    for (int j = 0; j < 4; j++) {
      int c = t + 256 * j;
      int srow = c >> 4;
      int dv8 = (c & 15) * 8;
      bf16x8 v = *(const bf16x8*)(KVB + (size_t)(s0 + srow) * 4096 + h * 256 + 128 + dv8);
      int sc = srow >> 3, sl = srow & 7;
#pragma unroll
      for (int i = 0; i < 8; i++) {
        int dv = dv8 + i;
        Vs[dv][((sc ^ ((dv >> 3) & 7)) << 3) | sl] = ((__hip_bfloat16*)&v)[i];
      }
    }
    __syncthreads();

    // S = Q K^T  (16x64 per wave, K-dim 192 = 6 MFMA steps)
    f32x4 sa[4];
#pragma unroll
    for (int nf = 0; nf < 4; nf++) sa[nf] = f32x4{0.f, 0.f, 0.f, 0.f};
#pragma unroll
    for (int ks = 0; ks < 6; ks++) {
#pragma unroll
      for (int nf = 0; nf < 4; nf++) {
        bf16x8 b = *(bf16x8*)&Ks[nf * 16 + lr][ks * 32 + lh * 8];
        sa[nf] = __builtin_amdgcn_mfma_f32_16x16x32_bf16(aq[ks], b, sa[nf], 0, 0, 0);
      }
    }
    // scale + causal mask
    float sv[4][4];
    const bool diag = (kb == bm);
#pragma unroll
    for (int nf = 0; nf < 4; nf++) {
      int scol = s0 + nf * 16 + lr;
#pragma unroll
      for (int j = 0; j < 4; j++) {
        float x = sa[nf][j] * ATTN_SCALE;
        if (diag) {
          int qr = bm * 64 + w * 16 + lh * 4 + j;
          if (scol > qr) x = -1e30f;
        }
        sv[nf][j] = x;
      }
    }
    // online softmax (rows live across 16 lanes sharing lh)
    float pm[4], fac[4];
#pragma unroll
    for (int j = 0; j < 4; j++) {
      float mx = fmaxf(fmaxf(sv[0][j], sv[1][j]), fmaxf(sv[2][j], sv[3][j]));
#pragma unroll
      for (int d = 1; d < 16; d <<= 1) mx = fmaxf(mx, __shfl_xor(mx, d, 64));
      float mn = fmaxf(m_run[j], mx);
      fac[j] = __expf(m_run[j] - mn);
      m_run[j] = mn;
      pm[j] = mn;
    }
    float rs[4] = {0.f, 0.f, 0.f, 0.f};
#pragma unroll
    for (int nf = 0; nf < 4; nf++) {
#pragma unroll
      for (int j = 0; j < 4; j++) {
        float p = __expf(sv[nf][j] - pm[j]);
        rs[j] += p;
        Ps[w][lh * 4 + j][nf * 16 + lr] = __float2bfloat16(p);
      }
    }
#pragma unroll
    for (int j = 0; j < 4; j++) {
      float s = rs[j];
#pragma unroll
      for (int d = 1; d < 16; d <<= 1) s += __shfl_xor(s, d, 64);
      l_run[j] = l_run[j] * fac[j] + s;
    }
#pragma unroll
    for (int nf = 0; nf < 8; nf++)
#pragma unroll
      for (int j = 0; j < 4; j++) o_acc[nf][j] *= fac[j];

    // PV: O += P[16x64] * V[64x128]
#pragma unroll
    for (int ks = 0; ks < 2; ks++) {
      bf16x8 pa = *(bf16x8*)&Ps[w][lr][ks * 32 + lh * 8];
#pragma unroll
      for (int nf = 0; nf < 8; nf++) {
        int dv = nf * 16 + lr;
        int c8 = ks * 4 + lh;
        bf16x8 vb = *(bf16x8*)&Vs[dv][((c8 ^ ((dv >> 3) & 7)) << 3)];
        o_acc[nf] = __builtin_amdgcn_mfma_f32_16x16x32_bf16(pa, vb, o_acc[nf], 0, 0, 0);
      }
    }
    __syncthreads();
  }
  // epilogue: normalize and store
#pragma unroll
  for (int nf = 0; nf < 8; nf++) {
    int col = h * 128 + nf * 16 + lr;
#pragma unroll
    for (int j = 0; j < 4; j++) {
      int row = bm * 64 + w * 16 + lh * 4 + j;
      Out[(size_t)row * 2048 + col] = __float2bfloat16(o_acc[nf][j] / l_run[j]);
    }
  }
}

// ----------------------------------------------------------------------------------------
extern "C" void kernel_launch(void* const* d_in, const int* in_sizes, int n_in,
                              void* d_out, int out_size, void* d_ws, size_t ws_size,
                              hipStream_t stream) {
  const float* hidden  = (const float*)d_in[1];
  const float* wq_a    = (const float*)d_in[2];
  const float* q_a_ln  = (const float*)d_in[3];
  const float* wq_b    = (const float*)d_in[4];
  const float* wkv_a   = (const float*)d_in[5];
  const float* kv_a_ln = (const float*)d_in[6];
  const float* wkv_b   = (const float*)d_in[7];
  const float* wo      = (const float*)d_in[8];
  float* out = (float*)d_out;

  char* ws = (char*)d_ws;
  size_t off = 0;
  auto alloc = [&](size_t bytes) { void* p = ws + off; off += (bytes + 255) & ~(size_t)255; return p; };
  __hip_bfloat16* h_bf    = (__hip_bfloat16*)alloc((size_t)2048 * 5120 * 2);
  __hip_bfloat16* qkvw_t  = (__hip_bfloat16*)alloc((size_t)2112 * 5120 * 2);  // [wq_a^T ; wkv_a^T]
  __hip_bfloat16* wq_b_t  = (__hip_bfloat16*)alloc((size_t)3072 * 1536 * 2);
  __hip_bfloat16* wkv_b_t = (__hip_bfloat16*)alloc((size_t)4096 * 512 * 2);
  __hip_bfloat16* wo_t    = (__hip_bfloat16*)alloc((size_t)5120 * 2048 * 2);
  float*          qkv_lat = (float*)alloc((size_t)2048 * 2112 * 4);
  __hip_bfloat16* q_a_bf  = (__hip_bfloat16*)alloc((size_t)2048 * 1536 * 2);
  __hip_bfloat16* ckv_bf  = (__hip_bfloat16*)alloc((size_t)2048 * 512 * 2);
  __hip_bfloat16* kpe_bf  = (__hip_bfloat16*)alloc((size_t)2048 * 64 * 2);
  __hip_bfloat16* q_bf    = (__hip_bfloat16*)alloc((size_t)2048 * 3072 * 2);
  __hip_bfloat16* kvb_bf  = (__hip_bfloat16*)alloc((size_t)2048 * 4096 * 2);
  __hip_bfloat16* attn_o  = (__hip_bfloat16*)alloc((size_t)2048 * 2048 * 2);
  (void)ws_size; (void)in_sizes; (void)n_in; (void)out_size;

  // conversions (wq_a and wkv_a transpose into ONE concatenated weight buffer)
  cvt_kernel<<<1024, 256, 0, stream>>>(hidden, h_bf, 2048 * 5120);
  transpose_cvt_kernel<<<dim3(160, 48), 256, 0, stream>>>(wq_a, qkvw_t, 5120, 1536);
  transpose_cvt_kernel<<<dim3(160, 18), 256, 0, stream>>>(wkv_a, qkvw_t + (size_t)1536 * 5120, 5120, 576);
  transpose_cvt_kernel<<<dim3(48, 96), 256, 0, stream>>>(wq_b, wq_b_t, 1536, 3072);
  transpose_cvt_kernel<<<dim3(16, 128), 256, 0, stream>>>(wkv_b, wkv_b_t, 512, 4096);
  transpose_cvt_kernel<<<dim3(64, 160), 256, 0, stream>>>(wo, wo_t, 2048, 5120);

  // fused: [q_latent | kv] = hidden @ [wq_a | wkv_a]   (N = 1536 + 576 = 2112)
  gemm_lds_kernel<false><<<dim3(16, 17), 256, 0, stream>>>(h_bf, qkvw_t, qkv_lat, 2048, 2112, 5120);

  // norms + k rope
  rmsnorm_kernel<<<2048, 256, 0, stream>>>(qkv_lat, 2112, 1536, q_a_ln, q_a_bf, 1536);
  rmsnorm_kernel<<<2048, 256, 0, stream>>>(qkv_lat + 1536, 2112, 512, kv_a_ln, ckv_bf, 512);
  rope_k_kernel<<<2048, 64, 0, stream>>>(qkv_lat + 2048, 2112, kpe_bf);

  // q = q_a_norm @ wq_b, rope pe slices in-place
  gemm_lds_kernel<true><<<dim3(16, 24), 256, 0, stream>>>(q_a_bf, wq_b_t, q_bf, 2048, 3072, 1536);
  rope_q_kernel<<<2048, 256, 0, stream>>>(q_bf);

  // kvb = c_kv @ wkv_b (k_nope | v per head)
  gemm_lds_kernel<true><<<dim3(16, 32), 256, 0, stream>>>(ckv_bf, wkv_b_t, kvb_bf, 2048, 4096, 512);

  // causal flash attention (round-1 proven kernel)
  attn_kernel<<<dim3(32, 16), 256, 0, stream>>>(q_bf, kvb_bf, kpe_bf, attn_o);

  // final projection
  gemm_lds_kernel<false><<<dim3(16, 40), 256, 0, stream>>>(attn_o, wo_t, out, 2048, 5120, 2048);
}

// Round 5
// 545.274 us; speedup vs baseline: 1.1352x; 1.0049x over previous
//
#include <hip/hip_runtime.h>
#include <hip/hip_bf16.h>

typedef __attribute__((ext_vector_type(8))) short bf16x8;
typedef __attribute__((ext_vector_type(4))) short bf16x4;
typedef __attribute__((ext_vector_type(4))) float f32x4;

typedef __attribute__((address_space(1))) const unsigned int gu32;
typedef __attribute__((address_space(3))) unsigned int lu32;

#define ATTN_SCALE 0.07216878364870323f  // (128+64)^-0.5

static __device__ __forceinline__ float bf2f(__hip_bfloat16 b) { return __bfloat162float(b); }

// ---------------------------------------------------------------- convert f32 -> bf16
__global__ void cvt_kernel(const float* __restrict__ in, __hip_bfloat16* __restrict__ out, int n) {
  for (int i = (blockIdx.x * 256 + threadIdx.x) * 4; i < n; i += gridDim.x * 256 * 4) {
    float4 v = *(const float4*)(in + i);
    out[i + 0] = __float2bfloat16(v.x);
    out[i + 1] = __float2bfloat16(v.y);
    out[i + 2] = __float2bfloat16(v.z);
    out[i + 3] = __float2bfloat16(v.w);
  }
}

// ------------------------------------------- transpose + convert: in[R][C] f32 -> out[C][R] bf16
__global__ void transpose_cvt_kernel(const float* __restrict__ in, __hip_bfloat16* __restrict__ out,
                                     int R, int C) {
  __shared__ float tile[32][33];
  int bi = blockIdx.x, bj = blockIdx.y;
  int tx = threadIdx.x & 31, ty = threadIdx.x >> 5;  // ty 0..7
#pragma unroll
  for (int k2 = 0; k2 < 4; k2++) {
    int r = bi * 32 + ty + k2 * 8;
    tile[ty + k2 * 8][tx] = in[(size_t)r * C + bj * 32 + tx];
  }
  __syncthreads();
#pragma unroll
  for (int k2 = 0; k2 < 4; k2++) {
    int cc = bj * 32 + ty + k2 * 8;
    out[(size_t)cc * R + bi * 32 + tx] = __float2bfloat16(tile[tx][ty + k2 * 8]);
  }
}

// ---------------------------------------------------------------- RMSNorm (f32 in, bf16 out)
__global__ void rmsnorm_kernel(const float* __restrict__ in, int in_stride, int cols,
                               const float* __restrict__ wgt,
                               __hip_bfloat16* __restrict__ out, int out_stride) {
  int row = blockIdx.x;
  const float* x = in + (size_t)row * in_stride;
  float ss = 0.f;
  for (int c = threadIdx.x; c < cols; c += 256) { float v = x[c]; ss += v * v; }
#pragma unroll
  for (int d = 1; d < 64; d <<= 1) ss += __shfl_xor(ss, d, 64);
  __shared__ float red[4];
  if ((threadIdx.x & 63) == 0) red[threadIdx.x >> 6] = ss;
  __syncthreads();
  float tot = red[0] + red[1] + red[2] + red[3];
  float r = rsqrtf(tot / cols + 1e-6f);
  __hip_bfloat16* o = out + (size_t)row * out_stride;
  for (int c = threadIdx.x; c < cols; c += 256)
    o[c] = __float2bfloat16(x[c] * r * wgt[c]);
}

// ---------------------------------------------------------------- RoPE on q (bf16 in-place)
__global__ void rope_q_kernel(__hip_bfloat16* __restrict__ q) {
  int row = blockIdx.x;
#pragma unroll
  for (int jj = 0; jj < 2; jj++) {
    int v = threadIdx.x + 256 * jj;  // 0..511
    int h = v >> 5, i = v & 31;
    float inv = powf(10000.f, -(2.f * i) / 64.f);
    float fr = (float)row * inv;
    float s, c;
    sincosf(fr, &s, &c);
    __hip_bfloat16* p = q + (size_t)row * 3072 + h * 192 + 128 + 2 * i;
    float x1 = bf2f(p[0]), x2 = bf2f(p[1]);
    p[0] = __float2bfloat16(x1 * c - x2 * s);
    p[1] = __float2bfloat16(x2 * c + x1 * s);
  }
}

// ---------------------------------------------------------------- RoPE on k_pe (f32 src -> bf16)
__global__ void rope_k_kernel(const float* __restrict__ src, int stride,
                              __hip_bfloat16* __restrict__ kpe) {
  int row = blockIdx.x;
  int i = threadIdx.x;
  if (i < 32) {
    float inv = powf(10000.f, -(2.f * i) / 64.f);
    float fr = (float)row * inv;
    float s, c;
    sincosf(fr, &s, &c);
    float x1 = src[(size_t)row * stride + 2 * i];
    float x2 = src[(size_t)row * stride + 2 * i + 1];
    kpe[(size_t)row * 64 + 2 * i]     = __float2bfloat16(x1 * c - x2 * s);
    kpe[(size_t)row * 64 + 2 * i + 1] = __float2bfloat16(x2 * c + x1 * s);
  }
}

// ---------------------------------------------------------------- GEMM: C[M][N] = A[M][K] * Bt[N][K]^T
// m97-style: global_load_lds(16B) staging, linear [128][32] LDS double-buffered,
// ONE barrier per K-step (DMA for k+1 issued right after the barrier, drained at next barrier).
// MODE: 0 = f32 row-major out; 1 = bf16 row-major out;
//       2 = split-kv epilogue: even bn-tiles -> Knope[t][h*128+d], odd -> Vt[h*128+dv][t].
template <int MODE>
__global__ __launch_bounds__(256, 2) void gemm_lds_kernel(
    const __hip_bfloat16* __restrict__ A, const __hip_bfloat16* __restrict__ Bt,
    void* __restrict__ Cout, __hip_bfloat16* __restrict__ KnopeOut,
    __hip_bfloat16* __restrict__ VtOut, int M, int N, int K) {
  __shared__ __hip_bfloat16 As[2][128][32];
  __shared__ __hip_bfloat16 Bs[2][128][32];
  const int t = threadIdx.x;
  const int w = t >> 6, l = t & 63;
  const int lr = l & 15, lh = l >> 4;
  const int wr = w >> 1, wc = w & 1;
  const int bm = blockIdx.x, bn = blockIdx.y;

  // staging: tile = 8 chunks of 1KB; wave w writes chunks {w, w+4}.
  // lane l -> row (l>>2) within chunk, col (l&3)*8; LDS offset == wave_base + l*16 (linear rule).
  const int r0 = l >> 2;
  const int c0 = (l & 3) * 8;
  const int rowA0 = w * 16 + r0;
  const int rowA1 = (4 + w) * 16 + r0;
  const __hip_bfloat16* Ag0 = A + (size_t)(bm * 128 + rowA0) * K + c0;
  const __hip_bfloat16* Ag1 = A + (size_t)(bm * 128 + rowA1) * K + c0;
  int br0 = bn * 128 + rowA0; if (br0 >= N) br0 = N - 1;  // clamp: junk cols never stored
  int br1 = bn * 128 + rowA1; if (br1 >= N) br1 = N - 1;
  const __hip_bfloat16* Bg0 = Bt + (size_t)br0 * K + c0;
  const __hip_bfloat16* Bg1 = Bt + (size_t)br1 * K + c0;

  f32x4 acc[4][4];
#pragma unroll
  for (int i = 0; i < 4; i++)
#pragma unroll
    for (int j = 0; j < 4; j++) acc[i][j] = f32x4{0.f, 0.f, 0.f, 0.f};

  auto issue = [&](int kt, int buf) {
    const int ko = kt * 32;
    __builtin_amdgcn_global_load_lds((gu32*)(Ag0 + ko), (lu32*)&As[buf][rowA0][c0], 16, 0, 0);
    __builtin_amdgcn_global_load_lds((gu32*)(Ag1 + ko), (lu32*)&As[buf][rowA1][c0], 16, 0, 0);
    __builtin_amdgcn_global_load_lds((gu32*)(Bg0 + ko), (lu32*)&Bs[buf][rowA0][c0], 16, 0, 0);
    __builtin_amdgcn_global_load_lds((gu32*)(Bg1 + ko), (lu32*)&Bs[buf][rowA1][c0], 16, 0, 0);
  };

  const int KT = K >> 5;
  issue(0, 0);
  int cur = 0;
  for (int kt = 0; kt < KT; ++kt) {
    __syncthreads();  // drains this wave's DMA -> buf `cur` ready; all waves past reads of cur^1
    if (kt + 1 < KT) issue(kt + 1, cur ^ 1);  // overlaps with compute; drains at next barrier
    bf16x8 af[4], bff[4];
#pragma unroll
    for (int m = 0; m < 4; m++) af[m] = *(bf16x8*)&As[cur][wr * 64 + m * 16 + lr][lh * 8];
#pragma unroll
    for (int n = 0; n < 4; n++) bff[n] = *(bf16x8*)&Bs[cur][wc * 64 + n * 16 + lr][lh * 8];
    __builtin_amdgcn_s_setprio(1);
#pragma unroll
    for (int m = 0; m < 4; m++)
#pragma unroll
      for (int n = 0; n < 4; n++)
        acc[m][n] = __builtin_amdgcn_mfma_f32_16x16x32_bf16(af[m], bff[n], acc[m][n], 0, 0, 0);
    __builtin_amdgcn_s_setprio(0);
    cur ^= 1;
  }
#pragma unroll
  for (int m = 0; m < 4; m++) {
    int row = bm * 128 + wr * 64 + m * 16 + lh * 4;
#pragma unroll
    for (int n = 0; n < 4; n++) {
      int col = bn * 128 + wc * 64 + n * 16 + lr;
      if (MODE == 2) {
        // kvb split epilogue: head h = col>>8; within-head col = col&255.
        int hcol = ((col >> 8) << 7) + (col & 127);  // h*128 + (d or dv)
        if ((bn & 1) == 0) {
          // k_nope -> Knope[t][h*128+d]
#pragma unroll
          for (int j = 0; j < 4; j++)
            KnopeOut[(size_t)(row + j) * 2048 + hcol] = __float2bfloat16(acc[m][n][j]);
        } else {
          // v -> Vt[h*128+dv][t], 4 consecutive t => one 8B store
          bf16x4 pk;
#pragma unroll
          for (int j = 0; j < 4; j++) {
            union { __hip_bfloat16 b; short s; } cv;
            cv.b = __float2bfloat16(acc[m][n][j]);
            pk[j] = cv.s;
          }
          *(bf16x4*)(VtOut + (size_t)hcol * 2048 + row) = pk;
        }
      } else if (col < N) {
#pragma unroll
        for (int j = 0; j < 4; j++) {
          if (MODE == 1)
            ((__hip_bfloat16*)Cout)[(size_t)(row + j) * N + col] = __float2bfloat16(acc[m][n][j]);
          else
            ((float*)Cout)[(size_t)(row + j) * N + col] = acc[m][n][j];
        }
      }
    }
  }
}

// ---------------------------------------------------------------- flash attention (causal)
// Q[T][3072] roped; Knope[T][2048] (h*128+d); Vt[2048][2048] ([h*128+dv][t]); KPE[T][64].
// Out[T][2048]. Block = (64 q-rows, 1 head), 4 waves x 16 rows, k-blocks of 64.
// Round-1 LDS layouts kept verbatim; adds T14 reg-prefetch of next tile + vectorized V staging.
__global__ __launch_bounds__(256, 2) void attn_kernel(
    const __hip_bfloat16* __restrict__ Q, const __hip_bfloat16* __restrict__ Knope,
    const __hip_bfloat16* __restrict__ Vt, const __hip_bfloat16* __restrict__ KPE,
    __hip_bfloat16* __restrict__ Out) {
  __shared__ __hip_bfloat16 Ks[64][200];     // K rows (192 feat + pad)
  __shared__ __hip_bfloat16 Vs[128][72];     // V transposed [dv][s], chunk-swizzled in s
  __shared__ __hip_bfloat16 Ps[4][16][72];   // per-wave P slab

  const int t = threadIdx.x;
  const int w = t >> 6, l = t & 63;
  const int lr = l & 15, lh = l >> 4;
  const int bm = (int)gridDim.x - 1 - (int)blockIdx.x;  // heavy blocks first
  const int h = blockIdx.y;

  // Q fragments held in registers for the whole kernel
  bf16x8 aq[6];
  {
    const int qrow = bm * 64 + w * 16 + lr;
    const __hip_bfloat16* qp = Q + (size_t)qrow * 3072 + h * 192 + lh * 8;
#pragma unroll
    for (int ks = 0; ks < 6; ks++) aq[ks] = *(const bf16x8*)(qp + ks * 32);
  }

  f32x4 o_acc[8];
#pragma unroll
  for (int i = 0; i < 8; i++) o_acc[i] = f32x4{0.f, 0.f, 0.f, 0.f};
  float m_run[4], l_run[4];
#pragma unroll
  for (int j = 0; j < 4; j++) { m_run[j] = -INFINITY; l_run[j] = 0.f; }

  bf16x8 kreg[6], vreg[4];
  auto load_regs = [&](int kb) {
    const int s0 = kb * 64;
#pragma unroll
    for (int j = 0; j < 6; j++) {
      int c = t + 256 * j;
      int row = c / 24, col8 = (c % 24) * 8;
      const __hip_bfloat16* src = (col8 < 128)
          ? Knope + (size_t)(s0 + row) * 2048 + h * 128 + col8
          : KPE + (size_t)(s0 + row) * 64 + (col8 - 128);
      kreg[j] = *(const bf16x8*)src;
    }
#pragma unroll
    for (int j = 0; j < 4; j++) {
      int c = t + 256 * j;     // 0..1023
      int dv = c >> 3;         // 0..127
      int sc = c & 7;          // s-chunk of 8
      vreg[j] = *(const bf16x8*)(Vt + (size_t)(h * 128 + dv) * 2048 + s0 + sc * 8);
    }
  };
  auto store_tile = [&]() {
#pragma unroll
    for (int j = 0; j < 6; j++) {
      int c = t + 256 * j;
      int row = c / 24, col8 = (c % 24) * 8;
      *(bf16x8*)&Ks[row][col8] = kreg[j];
    }
#pragma unroll
    for (int j = 0; j < 4; j++) {
      int c = t + 256 * j;
      int dv = c >> 3, sc = c & 7;
      *(bf16x8*)&Vs[dv][(sc ^ ((dv >> 3) & 7)) << 3] = vreg[j];
    }
  };

  load_regs(0);
  for (int kb = 0; kb <= bm; ++kb) {
    const int s0 = kb * 64;
    store_tile();
    __syncthreads();  // LDS tile visible to all waves
    if (kb < bm) load_regs(kb + 1);  // T14: global loads overlap compute below

    // S = Q K^T  (16x64 per wave, K-dim 192 = 6 MFMA steps)
    f32x4 sa[4];
#pragma unroll
    for (int nf = 0; nf < 4; nf++) sa[nf] = f32x4{0.f, 0.f, 0.f, 0.f};
#pragma unroll
    for (int ks = 0; ks < 6; ks++) {
#pragma unroll
      for (int nf = 0; nf < 4; nf++) {
        bf16x8 b = *(bf16x8*)&Ks[nf * 16 + lr][ks * 32 + lh * 8];
        sa[nf] = __builtin_amdgcn_mfma_f32_16x16x32_bf16(aq[ks], b, sa[nf], 0, 0, 0);
      }
    }
    // scale + causal mask
    float sv[4][4];
    const bool diag = (kb == bm);
#pragma unroll
    for (int nf = 0; nf < 4; nf++) {
      int scol = s0 + nf * 16 + lr;
#pragma unroll
      for (int j = 0; j < 4; j++) {
        float x = sa[nf][j] * ATTN_SCALE;
        if (diag) {
          int qr = bm * 64 + w * 16 + lh * 4 + j;
          if (scol > qr) x = -1e30f;
        }
        sv[nf][j] = x;
      }
    }
    // online softmax (rows live across 16 lanes sharing lh)
    float pm[4], fac[4];
#pragma unroll
    for (int j = 0; j < 4; j++) {
      float mx = fmaxf(fmaxf(sv[0][j], sv[1][j]), fmaxf(sv[2][j], sv[3][j]));
#pragma unroll
      for (int d = 1; d < 16; d <<= 1) mx = fmaxf(mx, __shfl_xor(mx, d, 64));
      float mn = fmaxf(m_run[j], mx);
      fac[j] = __expf(m_run[j] - mn);
      m_run[j] = mn;
      pm[j] = mn;
    }
    float rs[4] = {0.f, 0.f, 0.f, 0.f};
#pragma unroll
    for (int nf = 0; nf < 4; nf++) {
#pragma unroll
      for (int j = 0; j < 4; j++) {
        float p = __expf(sv[nf][j] - pm[j]);
        rs[j] += p;
        Ps[w][lh * 4 + j][nf * 16 + lr] = __float2bfloat16(p);
      }
    }
#pragma unroll
    for (int j = 0; j < 4; j++) {
      float s = rs[j];
#pragma unroll
      for (int d = 1; d < 16; d <<= 1) s += __shfl_xor(s, d, 64);
      l_run[j] = l_run[j] * fac[j] + s;
    }
#pragma unroll
    for (int nf = 0; nf < 8; nf++)
#pragma unroll
      for (int j = 0; j < 4; j++) o_acc[nf][j] *= fac[j];

    // PV: O += P[16x64] * V[64x128]
#pragma unroll
    for (int ks = 0; ks < 2; ks++) {
      bf16x8 pa = *(bf16x8*)&Ps[w][lr][ks * 32 + lh * 8];
#pragma unroll
      for (int nf = 0; nf < 8; nf++) {
        int dv = nf * 16 + lr;
        int c8 = ks * 4 + lh;
        bf16x8 vb = *(bf16x8*)&Vs[dv][((c8 ^ ((dv >> 3) & 7)) << 3)];
        o_acc[nf] = __builtin_amdgcn_mfma_f32_16x16x32_bf16(pa, vb, o_acc[nf], 0, 0, 0);
      }
    }
    __syncthreads();  // all waves done reading LDS before next store_tile overwrites
  }
  // epilogue: normalize and store
#pragma unroll
  for (int nf = 0; nf < 8; nf++) {
    int col = h * 128 + nf * 16 + lr;
#pragma unroll
    for (int j = 0; j < 4; j++) {
      int row = bm * 64 + w * 16 + lh * 4 + j;
      Out[(size_t)row * 2048 + col] = __float2bfloat16(o_acc[nf][j] / l_run[j]);
    }
  }
}

// ----------------------------------------------------------------------------------------
extern "C" void kernel_launch(void* const* d_in, const int* in_sizes, int n_in,
                              void* d_out, int out_size, void* d_ws, size_t ws_size,
                              hipStream_t stream) {
  const float* hidden  = (const float*)d_in[1];
  const float* wq_a    = (const float*)d_in[2];
  const float* q_a_ln  = (const float*)d_in[3];
  const float* wq_b    = (const float*)d_in[4];
  const float* wkv_a   = (const float*)d_in[5];
  const float* kv_a_ln = (const float*)d_in[6];
  const float* wkv_b   = (const float*)d_in[7];
  const float* wo      = (const float*)d_in[8];
  float* out = (float*)d_out;

  char* ws = (char*)d_ws;
  size_t off = 0;
  auto alloc = [&](size_t bytes) { void* p = ws + off; off += (bytes + 255) & ~(size_t)255; return p; };
  __hip_bfloat16* h_bf     = (__hip_bfloat16*)alloc((size_t)2048 * 5120 * 2);
  __hip_bfloat16* qkvw_t   = (__hip_bfloat16*)alloc((size_t)2112 * 5120 * 2);  // [wq_a^T ; wkv_a^T]
  __hip_bfloat16* wq_b_t   = (__hip_bfloat16*)alloc((size_t)3072 * 1536 * 2);
  __hip_bfloat16* wkv_b_t  = (__hip_bfloat16*)alloc((size_t)4096 * 512 * 2);
  __hip_bfloat16* wo_t     = (__hip_bfloat16*)alloc((size_t)5120 * 2048 * 2);
  float*          qkv_lat  = (float*)alloc((size_t)2048 * 2112 * 4);
  __hip_bfloat16* q_a_bf   = (__hip_bfloat16*)alloc((size_t)2048 * 1536 * 2);
  __hip_bfloat16* ckv_bf   = (__hip_bfloat16*)alloc((size_t)2048 * 512 * 2);
  __hip_bfloat16* kpe_bf   = (__hip_bfloat16*)alloc((size_t)2048 * 64 * 2);
  __hip_bfloat16* q_bf     = (__hip_bfloat16*)alloc((size_t)2048 * 3072 * 2);
  __hip_bfloat16* knope_bf = (__hip_bfloat16*)alloc((size_t)2048 * 2048 * 2);
  __hip_bfloat16* vt_bf    = (__hip_bfloat16*)alloc((size_t)2048 * 2048 * 2);  // [h*128+dv][t]
  __hip_bfloat16* attn_o   = (__hip_bfloat16*)alloc((size_t)2048 * 2048 * 2);
  (void)ws_size; (void)in_sizes; (void)n_in; (void)out_size;

  // conversions (wq_a and wkv_a transpose into ONE concatenated weight buffer)
  cvt_kernel<<<1024, 256, 0, stream>>>(hidden, h_bf, 2048 * 5120);
  transpose_cvt_kernel<<<dim3(160, 48), 256, 0, stream>>>(wq_a, qkvw_t, 5120, 1536);
  transpose_cvt_kernel<<<dim3(160, 18), 256, 0, stream>>>(wkv_a, qkvw_t + (size_t)1536 * 5120, 5120, 576);
  transpose_cvt_kernel<<<dim3(48, 96), 256, 0, stream>>>(wq_b, wq_b_t, 1536, 3072);
  transpose_cvt_kernel<<<dim3(16, 128), 256, 0, stream>>>(wkv_b, wkv_b_t, 512, 4096);
  transpose_cvt_kernel<<<dim3(64, 160), 256, 0, stream>>>(wo, wo_t, 2048, 5120);

  // fused: [q_latent | kv] = hidden @ [wq_a | wkv_a]   (N = 1536 + 576 = 2112)
  gemm_lds_kernel<0><<<dim3(16, 17), 256, 0, stream>>>(h_bf, qkvw_t, qkv_lat, nullptr, nullptr,
                                                       2048, 2112, 5120);

  // norms + k rope
  rmsnorm_kernel<<<2048, 256, 0, stream>>>(qkv_lat, 2112, 1536, q_a_ln, q_a_bf, 1536);
  rmsnorm_kernel<<<2048, 256, 0, stream>>>(qkv_lat + 1536, 2112, 512, kv_a_ln, ckv_bf, 512);
  rope_k_kernel<<<2048, 64, 0, stream>>>(qkv_lat + 2048, 2112, kpe_bf);

  // q = q_a_norm @ wq_b, rope pe slices in-place
  gemm_lds_kernel<1><<<dim3(16, 24), 256, 0, stream>>>(q_a_bf, wq_b_t, q_bf, nullptr, nullptr,
                                                       2048, 3072, 1536);
  rope_q_kernel<<<2048, 256, 0, stream>>>(q_bf);

  // kvb = c_kv @ wkv_b, split epilogue: k_nope row-major, V transposed
  gemm_lds_kernel<2><<<dim3(16, 32), 256, 0, stream>>>(ckv_bf, wkv_b_t, nullptr, knope_bf, vt_bf,
                                                       2048, 4096, 512);

  // causal flash attention
  attn_kernel<<<dim3(32, 16), 256, 0, stream>>>(q_bf, knope_bf, vt_bf, kpe_bf, attn_o);

  // final projection
  gemm_lds_kernel<0><<<dim3(16, 40), 256, 0, stream>>>(attn_o, wo_t, out, nullptr, nullptr,
                                                       2048, 5120, 2048);
}

// Round 6
// 522.440 us; speedup vs baseline: 1.1849x; 1.0437x over previous
//
#include <hip/hip_runtime.h>
#include <hip/hip_bf16.h>

typedef __attribute__((ext_vector_type(8))) short bf16x8;
typedef __attribute__((ext_vector_type(4))) short bf16x4;
typedef __attribute__((ext_vector_type(4))) float f32x4;

typedef __attribute__((address_space(1))) const unsigned int gu32;
typedef __attribute__((address_space(3))) unsigned int lu32;

#define ATTN_SCALE 0.07216878364870323f  // (128+64)^-0.5

static __device__ __forceinline__ float bf2f(__hip_bfloat16 b) { return __bfloat162float(b); }

// ---------------------------------------------------------------- convert f32 -> bf16
__global__ void cvt_kernel(const float* __restrict__ in, __hip_bfloat16* __restrict__ out, int n) {
  for (int i = (blockIdx.x * 256 + threadIdx.x) * 4; i < n; i += gridDim.x * 256 * 4) {
    float4 v = *(const float4*)(in + i);
    out[i + 0] = __float2bfloat16(v.x);
    out[i + 1] = __float2bfloat16(v.y);
    out[i + 2] = __float2bfloat16(v.z);
    out[i + 3] = __float2bfloat16(v.w);
  }
}

// ------------------------------------------- transpose + convert: in[R][C] f32 -> out[C][R] bf16
__global__ void transpose_cvt_kernel(const float* __restrict__ in, __hip_bfloat16* __restrict__ out,
                                     int R, int C) {
  __shared__ float tile[32][33];
  int bi = blockIdx.x, bj = blockIdx.y;
  int tx = threadIdx.x & 31, ty = threadIdx.x >> 5;  // ty 0..7
#pragma unroll
  for (int k2 = 0; k2 < 4; k2++) {
    int r = bi * 32 + ty + k2 * 8;
    tile[ty + k2 * 8][tx] = in[(size_t)r * C + bj * 32 + tx];
  }
  __syncthreads();
#pragma unroll
  for (int k2 = 0; k2 < 4; k2++) {
    int cc = bj * 32 + ty + k2 * 8;
    out[(size_t)cc * R + bi * 32 + tx] = __float2bfloat16(tile[tx][ty + k2 * 8]);
  }
}

// ---------------------------------------------------------------- RMSNorm (f32 in, bf16 out)
__global__ void rmsnorm_kernel(const float* __restrict__ in, int in_stride, int cols,
                               const float* __restrict__ wgt,
                               __hip_bfloat16* __restrict__ out, int out_stride) {
  int row = blockIdx.x;
  const float* x = in + (size_t)row * in_stride;
  float ss = 0.f;
  for (int c = threadIdx.x; c < cols; c += 256) { float v = x[c]; ss += v * v; }
#pragma unroll
  for (int d = 1; d < 64; d <<= 1) ss += __shfl_xor(ss, d, 64);
  __shared__ float red[4];
  if ((threadIdx.x & 63) == 0) red[threadIdx.x >> 6] = ss;
  __syncthreads();
  float tot = red[0] + red[1] + red[2] + red[3];
  float r = rsqrtf(tot / cols + 1e-6f);
  __hip_bfloat16* o = out + (size_t)row * out_stride;
  for (int c = threadIdx.x; c < cols; c += 256)
    o[c] = __float2bfloat16(x[c] * r * wgt[c]);
}

// ---------------------------------------------------------------- RoPE on q (bf16 in-place)
__global__ void rope_q_kernel(__hip_bfloat16* __restrict__ q) {
  int row = blockIdx.x;
#pragma unroll
  for (int jj = 0; jj < 2; jj++) {
    int v = threadIdx.x + 256 * jj;  // 0..511
    int h = v >> 5, i = v & 31;
    float inv = powf(10000.f, -(2.f * i) / 64.f);
    float fr = (float)row * inv;
    float s, c;
    sincosf(fr, &s, &c);
    __hip_bfloat16* p = q + (size_t)row * 3072 + h * 192 + 128 + 2 * i;
    float x1 = bf2f(p[0]), x2 = bf2f(p[1]);
    p[0] = __float2bfloat16(x1 * c - x2 * s);
    p[1] = __float2bfloat16(x2 * c + x1 * s);
  }
}

// ---------------------------------------------------------------- RoPE on k_pe (f32 src -> bf16)
__global__ void rope_k_kernel(const float* __restrict__ src, int stride,
                              __hip_bfloat16* __restrict__ kpe) {
  int row = blockIdx.x;
  int i = threadIdx.x;
  if (i < 32) {
    float inv = powf(10000.f, -(2.f * i) / 64.f);
    float fr = (float)row * inv;
    float s, c;
    sincosf(fr, &s, &c);
    float x1 = src[(size_t)row * stride + 2 * i];
    float x2 = src[(size_t)row * stride + 2 * i + 1];
    kpe[(size_t)row * 64 + 2 * i]     = __float2bfloat16(x1 * c - x2 * s);
    kpe[(size_t)row * 64 + 2 * i + 1] = __float2bfloat16(x2 * c + x1 * s);
  }
}

// ---------------------------------------------------------------- GEMM: C[M][N] = A[M][K] * Bt[N][K]^T
// m97-style: global_load_lds(16B) staging, linear [128][32] LDS double-buffered,
// ONE barrier per K-step (DMA for k+1 issued right after the barrier, drained at next barrier).
// MODE: 0 = f32 row-major out; 1 = bf16 row-major out;
//       2 = split-kv epilogue: even bn-tiles -> Knope[t][h*128+d], odd -> Vt[h*128+dv][t].
template <int MODE>
__global__ __launch_bounds__(256, 2) void gemm_lds_kernel(
    const __hip_bfloat16* __restrict__ A, const __hip_bfloat16* __restrict__ Bt,
    void* __restrict__ Cout, __hip_bfloat16* __restrict__ KnopeOut,
    __hip_bfloat16* __restrict__ VtOut, int M, int N, int K) {
  __shared__ __hip_bfloat16 As[2][128][32];
  __shared__ __hip_bfloat16 Bs[2][128][32];
  const int t = threadIdx.x;
  const int w = t >> 6, l = t & 63;
  const int lr = l & 15, lh = l >> 4;
  const int wr = w >> 1, wc = w & 1;
  const int bm = blockIdx.x, bn = blockIdx.y;

  const int r0 = l >> 2;
  const int c0 = (l & 3) * 8;
  const int rowA0 = w * 16 + r0;
  const int rowA1 = (4 + w) * 16 + r0;
  const __hip_bfloat16* Ag0 = A + (size_t)(bm * 128 + rowA0) * K + c0;
  const __hip_bfloat16* Ag1 = A + (size_t)(bm * 128 + rowA1) * K + c0;
  int br0 = bn * 128 + rowA0; if (br0 >= N) br0 = N - 1;  // clamp: junk cols never stored
  int br1 = bn * 128 + rowA1; if (br1 >= N) br1 = N - 1;
  const __hip_bfloat16* Bg0 = Bt + (size_t)br0 * K + c0;
  const __hip_bfloat16* Bg1 = Bt + (size_t)br1 * K + c0;

  f32x4 acc[4][4];
#pragma unroll
  for (int i = 0; i < 4; i++)
#pragma unroll
    for (int j = 0; j < 4; j++) acc[i][j] = f32x4{0.f, 0.f, 0.f, 0.f};

  auto issue = [&](int kt, int buf) {
    const int ko = kt * 32;
    __builtin_amdgcn_global_load_lds((gu32*)(Ag0 + ko), (lu32*)&As[buf][rowA0][c0], 16, 0, 0);
    __builtin_amdgcn_global_load_lds((gu32*)(Ag1 + ko), (lu32*)&As[buf][rowA1][c0], 16, 0, 0);
    __builtin_amdgcn_global_load_lds((gu32*)(Bg0 + ko), (lu32*)&Bs[buf][rowA0][c0], 16, 0, 0);
    __builtin_amdgcn_global_load_lds((gu32*)(Bg1 + ko), (lu32*)&Bs[buf][rowA1][c0], 16, 0, 0);
  };

  const int KT = K >> 5;
  issue(0, 0);
  int cur = 0;
  for (int kt = 0; kt < KT; ++kt) {
    __syncthreads();
    if (kt + 1 < KT) issue(kt + 1, cur ^ 1);
    bf16x8 af[4], bff[4];
#pragma unroll
    for (int m = 0; m < 4; m++) af[m] = *(bf16x8*)&As[cur][wr * 64 + m * 16 + lr][lh * 8];
#pragma unroll
    for (int n = 0; n < 4; n++) bff[n] = *(bf16x8*)&Bs[cur][wc * 64 + n * 16 + lr][lh * 8];
    __builtin_amdgcn_s_setprio(1);
#pragma unroll
    for (int m = 0; m < 4; m++)
#pragma unroll
      for (int n = 0; n < 4; n++)
        acc[m][n] = __builtin_amdgcn_mfma_f32_16x16x32_bf16(af[m], bff[n], acc[m][n], 0, 0, 0);
    __builtin_amdgcn_s_setprio(0);
    cur ^= 1;
  }
#pragma unroll
  for (int m = 0; m < 4; m++) {
    int row = bm * 128 + wr * 64 + m * 16 + lh * 4;
#pragma unroll
    for (int n = 0; n < 4; n++) {
      int col = bn * 128 + wc * 64 + n * 16 + lr;
      if (MODE == 2) {
        int hcol = ((col >> 8) << 7) + (col & 127);  // h*128 + (d or dv)
        if ((bn & 1) == 0) {
#pragma unroll
          for (int j = 0; j < 4; j++)
            KnopeOut[(size_t)(row + j) * 2048 + hcol] = __float2bfloat16(acc[m][n][j]);
        } else {
          bf16x4 pk;
#pragma unroll
          for (int j = 0; j < 4; j++) {
            union { __hip_bfloat16 b; short s; } cv;
            cv.b = __float2bfloat16(acc[m][n][j]);
            pk[j] = cv.s;
          }
          *(bf16x4*)(VtOut + (size_t)hcol * 2048 + row) = pk;
        }
      } else if (col < N) {
#pragma unroll
        for (int j = 0; j < 4; j++) {
          if (MODE == 1)
            ((__hip_bfloat16*)Cout)[(size_t)(row + j) * N + col] = __float2bfloat16(acc[m][n][j]);
          else
            ((float*)Cout)[(size_t)(row + j) * N + col] = acc[m][n][j];
        }
      }
    }
  }
}

// ---------------------------------------------------------------- flash attention (causal, KV-split)
// Q[T][3072] roped; Knope[T][2048]; Vt[2048][2048]; KPE[T][64]; Out[T][2048].
// Block = (64 q-rows, head, kv-chunk of <=8 k-blocks). 4 waves x 16 rows.
// q-tile bm has nch=(bm>>3)+1 chunks; single-chunk tiles write Out directly,
// multi-chunk tiles write unnormalized f32 partial O + per-row (m,l) for the combine pass.
// Partial slot indexing (per head, tiles bm>=8): base(bm) = {g=1:0, g=2:16, g=3:40} + (bm&7)*(g+1).
__global__ __launch_bounds__(256, 2) void attn_kernel(
    const __hip_bfloat16* __restrict__ Q, const __hip_bfloat16* __restrict__ Knope,
    const __hip_bfloat16* __restrict__ Vt, const __hip_bfloat16* __restrict__ KPE,
    __hip_bfloat16* __restrict__ Out, float* __restrict__ Opart, float2* __restrict__ MLpart) {
  __shared__ __hip_bfloat16 Ks[64][200];     // K rows (192 feat + pad)
  __shared__ __hip_bfloat16 Vs[128][72];     // V transposed [dv][s], chunk-swizzled in s
  __shared__ __hip_bfloat16 Ps[4][16][72];   // per-wave P slab

  const int t = threadIdx.x;
  const int w = t >> 6, l = t & 63;
  const int lr = l & 15, lh = l >> 4;
  const int h = blockIdx.y;

  // decode blockIdx.x (0..79) -> (bm, ci)
  const int x = blockIdx.x;
  const int g = (x >= 48) ? 3 : (x >= 24) ? 2 : (x >= 8) ? 1 : 0;
  const int Sg = (g == 3) ? 48 : (g == 2) ? 24 : (g == 1) ? 8 : 0;
  const int r = x - Sg;
  const int q = r / (g + 1);
  const int bm = g * 8 + q;
  const int ci = r - q * (g + 1);
  const int kb0 = ci * 8;
  const int kb_last = (bm < kb0 + 7) ? bm : kb0 + 7;
  const bool partial = (g > 0);

  // Q fragments held in registers for the whole kernel
  bf16x8 aq[6];
  {
    const int qrow = bm * 64 + w * 16 + lr;
    const __hip_bfloat16* qp = Q + (size_t)qrow * 3072 + h * 192 + lh * 8;
#pragma unroll
    for (int ks = 0; ks < 6; ks++) aq[ks] = *(const bf16x8*)(qp + ks * 32);
  }

  f32x4 o_acc[8];
#pragma unroll
  for (int i = 0; i < 8; i++) o_acc[i] = f32x4{0.f, 0.f, 0.f, 0.f};
  float m_run[4], l_run[4];
#pragma unroll
  for (int j = 0; j < 4; j++) { m_run[j] = -INFINITY; l_run[j] = 0.f; }

  bf16x8 kreg[6], vreg[4];
  auto load_regs = [&](int kb) {
    const int s0 = kb * 64;
#pragma unroll
    for (int j = 0; j < 6; j++) {
      int c = t + 256 * j;
      int row = c / 24, col8 = (c % 24) * 8;
      const __hip_bfloat16* src = (col8 < 128)
          ? Knope + (size_t)(s0 + row) * 2048 + h * 128 + col8
          : KPE + (size_t)(s0 + row) * 64 + (col8 - 128);
      kreg[j] = *(const bf16x8*)src;
    }
#pragma unroll
    for (int j = 0; j < 4; j++) {
      int c = t + 256 * j;     // 0..1023
      int dv = c >> 3;         // 0..127
      int sc = c & 7;          // s-chunk of 8
      vreg[j] = *(const bf16x8*)(Vt + (size_t)(h * 128 + dv) * 2048 + s0 + sc * 8);
    }
  };
  auto store_tile = [&]() {
#pragma unroll
    for (int j = 0; j < 6; j++) {
      int c = t + 256 * j;
      int row = c / 24, col8 = (c % 24) * 8;
      *(bf16x8*)&Ks[row][col8] = kreg[j];
    }
#pragma unroll
    for (int j = 0; j < 4; j++) {
      int c = t + 256 * j;
      int dv = c >> 3, sc = c & 7;
      *(bf16x8*)&Vs[dv][(sc ^ ((dv >> 3) & 7)) << 3] = vreg[j];
    }
  };

  load_regs(kb0);
  for (int kb = kb0; kb <= kb_last; ++kb) {
    const int s0 = kb * 64;
    store_tile();
    __syncthreads();  // LDS tile visible to all waves
    if (kb < kb_last) load_regs(kb + 1);  // T14: global loads overlap compute below

    // S = Q K^T  (16x64 per wave, K-dim 192 = 6 MFMA steps)
    f32x4 sa[4];
#pragma unroll
    for (int nf = 0; nf < 4; nf++) sa[nf] = f32x4{0.f, 0.f, 0.f, 0.f};
#pragma unroll
    for (int ks = 0; ks < 6; ks++) {
#pragma unroll
      for (int nf = 0; nf < 4; nf++) {
        bf16x8 b = *(bf16x8*)&Ks[nf * 16 + lr][ks * 32 + lh * 8];
        sa[nf] = __builtin_amdgcn_mfma_f32_16x16x32_bf16(aq[ks], b, sa[nf], 0, 0, 0);
      }
    }
    // scale + causal mask
    float sv[4][4];
    const bool diag = (kb == bm);
#pragma unroll
    for (int nf = 0; nf < 4; nf++) {
      int scol = s0 + nf * 16 + lr;
#pragma unroll
      for (int j = 0; j < 4; j++) {
        float xv = sa[nf][j] * ATTN_SCALE;
        if (diag) {
          int qr = bm * 64 + w * 16 + lh * 4 + j;
          if (scol > qr) xv = -1e30f;
        }
        sv[nf][j] = xv;
      }
    }
    // online softmax (rows live across 16 lanes sharing lh)
    float pm[4], fac[4];
#pragma unroll
    for (int j = 0; j < 4; j++) {
      float mx = fmaxf(fmaxf(sv[0][j], sv[1][j]), fmaxf(sv[2][j], sv[3][j]));
#pragma unroll
      for (int d = 1; d < 16; d <<= 1) mx = fmaxf(mx, __shfl_xor(mx, d, 64));
      float mn = fmaxf(m_run[j], mx);
      fac[j] = __expf(m_run[j] - mn);
      m_run[j] = mn;
      pm[j] = mn;
    }
    float rs[4] = {0.f, 0.f, 0.f, 0.f};
#pragma unroll
    for (int nf = 0; nf < 4; nf++) {
#pragma unroll
      for (int j = 0; j < 4; j++) {
        float p = __expf(sv[nf][j] - pm[j]);
        rs[j] += p;
        Ps[w][lh * 4 + j][nf * 16 + lr] = __float2bfloat16(p);
      }
    }
#pragma unroll
    for (int j = 0; j < 4; j++) {
      float s = rs[j];
#pragma unroll
      for (int d = 1; d < 16; d <<= 1) s += __shfl_xor(s, d, 64);
      l_run[j] = l_run[j] * fac[j] + s;
    }
#pragma unroll
    for (int nf = 0; nf < 8; nf++)
#pragma unroll
      for (int j = 0; j < 4; j++) o_acc[nf][j] *= fac[j];

    // PV: O += P[16x64] * V[64x128]
#pragma unroll
    for (int ks = 0; ks < 2; ks++) {
      bf16x8 pa = *(bf16x8*)&Ps[w][lr][ks * 32 + lh * 8];
#pragma unroll
      for (int nf = 0; nf < 8; nf++) {
        int dv = nf * 16 + lr;
        int c8 = ks * 4 + lh;
        bf16x8 vb = *(bf16x8*)&Vs[dv][((c8 ^ ((dv >> 3) & 7)) << 3)];
        o_acc[nf] = __builtin_amdgcn_mfma_f32_16x16x32_bf16(pa, vb, o_acc[nf], 0, 0, 0);
      }
    }
    __syncthreads();  // all waves done reading LDS before next store_tile overwrites
  }

  if (!partial) {
    // single-chunk tile: final normalized output
#pragma unroll
    for (int nf = 0; nf < 8; nf++) {
      int col = h * 128 + nf * 16 + lr;
#pragma unroll
      for (int j = 0; j < 4; j++) {
        int row = bm * 64 + w * 16 + lh * 4 + j;
        Out[(size_t)row * 2048 + col] = __float2bfloat16(o_acc[nf][j] / l_run[j]);
      }
    }
  } else {
    // partial: slot = h*72 + base(bm) + ci
    const int base = ((g == 1) ? 0 : (g == 2) ? 16 : 40) + q * (g + 1);
    const int slot = h * 72 + base + ci;
    float* op = Opart + (size_t)slot * 8192;  // [64][128]
#pragma unroll
    for (int nf = 0; nf < 8; nf++) {
      int col = nf * 16 + lr;
#pragma unroll
      for (int j = 0; j < 4; j++) {
        int row = w * 16 + lh * 4 + j;
        op[row * 128 + col] = o_acc[nf][j];
      }
    }
    if (lr == 0) {
#pragma unroll
      for (int j = 0; j < 4; j++) {
        int row = w * 16 + lh * 4 + j;
        MLpart[(size_t)slot * 64 + row] = float2{m_run[j], l_run[j]};
      }
    }
  }
}

// ---------------------------------------------------------------- combine partial attention chunks
// grid: x = 24 (bm 8..31), y = 16 heads; 256 threads. Thread handles one row x 32 cols.
__global__ void attn_combine_kernel(const float* __restrict__ Opart,
                                    const float2* __restrict__ MLpart,
                                    __hip_bfloat16* __restrict__ Out) {
  const int bm = 8 + blockIdx.x, h = blockIdx.y;
  const int g = bm >> 3;          // 1..3
  const int nch = g + 1;          // 2..4
  const int base = ((g == 1) ? 0 : (g == 2) ? 16 : 40) + (bm & 7) * nch;
  const int slot0 = h * 72 + base;
  const int row = threadIdx.x >> 2;
  const int c0 = (threadIdx.x & 3) * 32;

  float M = -INFINITY;
  for (int c = 0; c < nch; ++c) M = fmaxf(M, MLpart[(size_t)(slot0 + c) * 64 + row].x);
  float L = 0.f;
  for (int c = 0; c < nch; ++c) {
    float2 ml = MLpart[(size_t)(slot0 + c) * 64 + row];
    L += ml.y * __expf(ml.x - M);
  }
  float acc[32];
#pragma unroll
  for (int i = 0; i < 32; i++) acc[i] = 0.f;
  for (int c = 0; c < nch; ++c) {
    float2 ml = MLpart[(size_t)(slot0 + c) * 64 + row];
    float sc = __expf(ml.x - M);
    const float* op = Opart + (size_t)(slot0 + c) * 8192 + row * 128 + c0;
#pragma unroll
    for (int k = 0; k < 8; k++) {
      float4 v = *(const float4*)(op + k * 4);
      acc[k * 4 + 0] += sc * v.x;
      acc[k * 4 + 1] += sc * v.y;
      acc[k * 4 + 2] += sc * v.z;
      acc[k * 4 + 3] += sc * v.w;
    }
  }
  const float inv = 1.f / L;
  __hip_bfloat16* o = Out + (size_t)(bm * 64 + row) * 2048 + h * 128 + c0;
#pragma unroll
  for (int i = 0; i < 32; i++) o[i] = __float2bfloat16(acc[i] * inv);
}

// ----------------------------------------------------------------------------------------
extern "C" void kernel_launch(void* const* d_in, const int* in_sizes, int n_in,
                              void* d_out, int out_size, void* d_ws, size_t ws_size,
                              hipStream_t stream) {
  const float* hidden  = (const float*)d_in[1];
  const float* wq_a    = (const float*)d_in[2];
  const float* q_a_ln  = (const float*)d_in[3];
  const float* wq_b    = (const float*)d_in[4];
  const float* wkv_a   = (const float*)d_in[5];
  const float* kv_a_ln = (const float*)d_in[6];
  const float* wkv_b   = (const float*)d_in[7];
  const float* wo      = (const float*)d_in[8];
  float* out = (float*)d_out;

  char* ws = (char*)d_ws;
  size_t off = 0;
  auto alloc = [&](size_t bytes) { void* p = ws + off; off += (bytes + 255) & ~(size_t)255; return p; };
  __hip_bfloat16* h_bf     = (__hip_bfloat16*)alloc((size_t)2048 * 5120 * 2);
  __hip_bfloat16* qkvw_t   = (__hip_bfloat16*)alloc((size_t)2112 * 5120 * 2);  // [wq_a^T ; wkv_a^T]
  __hip_bfloat16* wq_b_t   = (__hip_bfloat16*)alloc((size_t)3072 * 1536 * 2);
  __hip_bfloat16* wkv_b_t  = (__hip_bfloat16*)alloc((size_t)4096 * 512 * 2);
  __hip_bfloat16* wo_t     = (__hip_bfloat16*)alloc((size_t)5120 * 2048 * 2);
  float*          qkv_lat  = (float*)alloc((size_t)2048 * 2112 * 4);
  __hip_bfloat16* q_a_bf   = (__hip_bfloat16*)alloc((size_t)2048 * 1536 * 2);
  __hip_bfloat16* ckv_bf   = (__hip_bfloat16*)alloc((size_t)2048 * 512 * 2);
  __hip_bfloat16* kpe_bf   = (__hip_bfloat16*)alloc((size_t)2048 * 64 * 2);
  __hip_bfloat16* q_bf     = (__hip_bfloat16*)alloc((size_t)2048 * 3072 * 2);
  __hip_bfloat16* knope_bf = (__hip_bfloat16*)alloc((size_t)2048 * 2048 * 2);
  __hip_bfloat16* vt_bf    = (__hip_bfloat16*)alloc((size_t)2048 * 2048 * 2);  // [h*128+dv][t]
  __hip_bfloat16* attn_o   = (__hip_bfloat16*)alloc((size_t)2048 * 2048 * 2);
  float*          opart    = (float*)alloc((size_t)1152 * 8192 * 4);           // 36.9 MB
  float2*         mlpart   = (float2*)alloc((size_t)1152 * 64 * 8);
  (void)ws_size; (void)in_sizes; (void)n_in; (void)out_size;

  // conversions (wq_a and wkv_a transpose into ONE concatenated weight buffer)
  cvt_kernel<<<1024, 256, 0, stream>>>(hidden, h_bf, 2048 * 5120);
  transpose_cvt_kernel<<<dim3(160, 48), 256, 0, stream>>>(wq_a, qkvw_t, 5120, 1536);
  transpose_cvt_kernel<<<dim3(160, 18), 256, 0, stream>>>(wkv_a, qkvw_t + (size_t)1536 * 5120, 5120, 576);
  transpose_cvt_kernel<<<dim3(48, 96), 256, 0, stream>>>(wq_b, wq_b_t, 1536, 3072);
  transpose_cvt_kernel<<<dim3(16, 128), 256, 0, stream>>>(wkv_b, wkv_b_t, 512, 4096);
  transpose_cvt_kernel<<<dim3(64, 160), 256, 0, stream>>>(wo, wo_t, 2048, 5120);

  // fused: [q_latent | kv] = hidden @ [wq_a | wkv_a]   (N = 1536 + 576 = 2112)
  gemm_lds_kernel<0><<<dim3(16, 17), 256, 0, stream>>>(h_bf, qkvw_t, qkv_lat, nullptr, nullptr,
                                                       2048, 2112, 5120);

  // norms + k rope
  rmsnorm_kernel<<<2048, 256, 0, stream>>>(qkv_lat, 2112, 1536, q_a_ln, q_a_bf, 1536);
  rmsnorm_kernel<<<2048, 256, 0, stream>>>(qkv_lat + 1536, 2112, 512, kv_a_ln, ckv_bf, 512);
  rope_k_kernel<<<2048, 64, 0, stream>>>(qkv_lat + 2048, 2112, kpe_bf);

  // q = q_a_norm @ wq_b, rope pe slices in-place
  gemm_lds_kernel<1><<<dim3(16, 24), 256, 0, stream>>>(q_a_bf, wq_b_t, q_bf, nullptr, nullptr,
                                                       2048, 3072, 1536);
  rope_q_kernel<<<2048, 256, 0, stream>>>(q_bf);

  // kvb = c_kv @ wkv_b, split epilogue: k_nope row-major, V transposed
  gemm_lds_kernel<2><<<dim3(16, 32), 256, 0, stream>>>(ckv_bf, wkv_b_t, nullptr, knope_bf, vt_bf,
                                                       2048, 4096, 512);

  // causal flash attention, KV-split (80 chunk-blocks per head) + combine
  attn_kernel<<<dim3(80, 16), 256, 0, stream>>>(q_bf, knope_bf, vt_bf, kpe_bf, attn_o,
                                                opart, mlpart);
  attn_combine_kernel<<<dim3(24, 16), 256, 0, stream>>>(opart, mlpart, attn_o);

  // final projection
  gemm_lds_kernel<0><<<dim3(16, 40), 256, 0, stream>>>(attn_o, wo_t, out, nullptr, nullptr,
                                                       2048, 5120, 2048);
}